// Round 10
// baseline (231.725 us; speedup 1.0000x reference)
//
#include <hip/hip_runtime.h>
#include <math.h>

#define N_NODES 50000
#define N_EDGES 800000
#define E_TOT   850000   /* edges + self loops */
#define IN_F    128
#define HEADS   4
#define OUT_F   32
#define HF      128      /* HEADS*OUT_F */
#define NEG_SLOPE 0.2f
#define ELLW    40       /* slots per node; P(deg>40 | Poisson 16) ~ 2e-9 */
#define OVF_CAP 4096
#define DEN_SLOTS 16     /* spread denominator atomics 16-way */

/* workspace layout (float offsets; int arrays cast in place) */
#define WS_G      0           /* g = h*exp(a_src): 50000*128 floats */
#define WS_ES     6400000     /* exp(a_src): 200,000 floats */
#define WS_ED     6600000     /* exp(a_dst): 200,000 floats */
#define WS_DEN    6800000     /* denom[16][4] */
#define WS_CNT    6830000     /* int[50000]  */
#define WS_ELL    6880000     /* int[50000*40] = 2,000,000 */
#define WS_OVFC   8880000     /* int[1] + pad */
#define WS_OVFS   8880064     /* int[OVF_CAP] */
#define WS_OVFD   8884160     /* int[OVF_CAP] */
#define NBLK_EDGE 3321        /* ceil(850000/256) */

static __device__ __forceinline__ float4 ld4(const float* p) {
    return *reinterpret_cast<const float4*>(p);
}

/* D1: GEMM + fused epilogue: g = (x@W^T)*exp(a_src), es/ed tables;
   zeroes cnt / ovf_cnt / denom for the following passes.
   block: 256 threads, 32 nodes; x read from global (broadcast, L1-resident),
   only the 16 KB W^T K-chunk lives in LDS -> 10 blocks/CU capacity. */
__global__ __launch_bounds__(256) void k_gemm_attprep(
    const float* __restrict__ x, const float* __restrict__ W,
    const float* __restrict__ att, float* __restrict__ g,
    float* __restrict__ es, float* __restrict__ ed,
    int* __restrict__ cnt, int* __restrict__ ovf_cnt,
    float* __restrict__ denom)
{
    __shared__ float wt[32 * 128];   /* 16 KB (K-chunk of W^T) */
    const int t  = threadIdx.x;
    const int n0 = blockIdx.x * 32;

    /* fold in: zero in-degree counters + overflow counter + denom slots */
    if (t < 32) {
        int z = n0 + t;
        if (z < N_NODES) cnt[z] = 0;
    }
    if (blockIdx.x == 0) {
        if (t == 0) *ovf_cnt = 0;
        if (t < DEN_SLOTS * 4) denom[t] = 0.f;
    }

    const int cg = t & 31;          /* 4 consecutive output cols */
    const int nr = t >> 5;          /* nodes nr + 8*ni, ni=0..3 */
    float4 acc[4];
    #pragma unroll
    for (int ni = 0; ni < 4; ++ni) acc[ni] = make_float4(0.f, 0.f, 0.f, 0.f);

    const float4* wt4 = reinterpret_cast<const float4*>(wt);
    const float4* x4  = reinterpret_cast<const float4*>(x);

    /* clamped row ids: branchless, keeps 32-lane broadcast property */
    int row[4];
    #pragma unroll
    for (int ni = 0; ni < 4; ++ni) {
        int n = n0 + nr + ni * 8;
        row[ni] = n < N_NODES ? n : N_NODES - 1;
    }

    for (int kt = 0; kt < 4; ++kt) {
        __syncthreads();
        {   /* stage W^T chunk: wt[kk][c] = W[c][kt*32+kk] */
            const int c = t >> 1, half = t & 1;
            #pragma unroll
            for (int i = 0; i < 4; ++i) {
                float4 wv = ld4(W + c * 128 + kt * 32 + half * 16 + i * 4);
                int kk = half * 16 + i * 4;
                wt[(kk + 0) * 128 + c] = wv.x;
                wt[(kk + 1) * 128 + c] = wv.y;
                wt[(kk + 2) * 128 + c] = wv.z;
                wt[(kk + 3) * 128 + c] = wv.w;
            }
        }
        __syncthreads();

        #pragma unroll
        for (int kk4 = 0; kk4 < 8; ++kk4) {
            float xv[4][4];
            #pragma unroll
            for (int ni = 0; ni < 4; ++ni)
                *reinterpret_cast<float4*>(xv[ni]) =
                    x4[row[ni] * 32 + kt * 8 + kk4];      /* broadcast load */
            #pragma unroll
            for (int j = 0; j < 4; ++j) {
                float4 wv = wt4[(kk4 * 4 + j) * 32 + cg];
                #pragma unroll
                for (int ni = 0; ni < 4; ++ni) {
                    acc[ni].x += xv[ni][j] * wv.x;
                    acc[ni].y += xv[ni][j] * wv.y;
                    acc[ni].z += xv[ni][j] * wv.z;
                    acc[ni].w += xv[ni][j] * wv.w;
                }
            }
        }
    }

    const int head = cg >> 3;
    const int f0   = (cg & 7) * 4;
    float4 as = ld4(att + head * 64 + f0);
    float4 ad = ld4(att + head * 64 + 32 + f0);

    #pragma unroll
    for (int ni = 0; ni < 4; ++ni) {
        int n = n0 + nr + ni * 8;
        if (n < N_NODES) {
            float lx = acc[ni].x > 0.f ? acc[ni].x : NEG_SLOPE * acc[ni].x;
            float ly = acc[ni].y > 0.f ? acc[ni].y : NEG_SLOPE * acc[ni].y;
            float lz = acc[ni].z > 0.f ? acc[ni].z : NEG_SLOPE * acc[ni].z;
            float lw = acc[ni].w > 0.f ? acc[ni].w : NEG_SLOPE * acc[ni].w;
            float ps = lx * as.x + ly * as.y + lz * as.z + lw * as.w;
            float pd = lx * ad.x + ly * ad.y + lz * ad.z + lw * ad.w;
            ps += __shfl_xor(ps, 1); ps += __shfl_xor(ps, 2); ps += __shfl_xor(ps, 4);
            pd += __shfl_xor(pd, 1); pd += __shfl_xor(pd, 2); pd += __shfl_xor(pd, 4);
            float esv = expf(ps);                      /* all 8 lanes agree */
            float4 gv = make_float4(acc[ni].x * esv, acc[ni].y * esv,
                                    acc[ni].z * esv, acc[ni].w * esv);
            *reinterpret_cast<float4*>(&g[n * 128 + cg * 4]) = gv;
            if ((t & 7) == 0) {
                es[n * 4 + head] = esv;
                ed[n * 4 + head] = expf(pd);
            }
        }
    }
}

/* D2: ONE edge pass: ELL slot assign (count+fill fused) + denominator
   partials into 16 denom slots (contention-spread atomics).
   threads [0,800K): real edges; [800K,850K): self-loop denominator terms. */
__global__ __launch_bounds__(256) void k_edge_fill_denom(
    const int* __restrict__ eidx, const float* __restrict__ es,
    const float* __restrict__ ed, int* __restrict__ cnt,
    int* __restrict__ ell, int* __restrict__ ovf_cnt,
    int* __restrict__ ovf_s, int* __restrict__ ovf_d,
    float* __restrict__ denom)
{
    __shared__ float4 red[256];
    const int t = threadIdx.x;
    const int e = blockIdx.x * 256 + t;
    float4 w = make_float4(0.f, 0.f, 0.f, 0.f);
    if (e < E_TOT) {
        int s, d;
        if (e < N_EDGES) {
            s = eidx[e]; d = eidx[N_EDGES + e];
            int pos = atomicAdd(&cnt[d], 1);
            if (pos < ELLW) {
                ell[d * ELLW + pos] = s;
            } else {
                int o = atomicAdd(ovf_cnt, 1);
                if (o < OVF_CAP) { ovf_s[o] = s; ovf_d[o] = d; }
            }
        } else {
            s = d = e - N_EDGES;          /* self loop: denom term only */
        }
        float4 vs = ld4(es + s * 4);
        float4 vd = ld4(ed + d * 4);
        w.x = vs.x * vd.x;
        w.y = vs.y * vd.y;
        w.z = vs.z * vd.z;
        w.w = vs.w * vd.w;
    }
    red[t] = w;
    __syncthreads();
    for (int sdt = 128; sdt > 0; sdt >>= 1) {
        if (t < sdt) {
            float4 o = red[t + sdt];
            red[t].x += o.x; red[t].y += o.y; red[t].z += o.z; red[t].w += o.w;
        }
        __syncthreads();
    }
    if (t < 4)
        atomicAdd(&denom[(blockIdx.x & (DEN_SLOTS - 1)) * 4 + t],
                  reinterpret_cast<const float*>(&red[0])[t]);
}

/* D3: gather (ELL): pure sparse row-sum of g, scale by ed[n]/denom, +bias.
   Overflow edges (expected none) folded in. */
__global__ __launch_bounds__(256) void k_gather(
    const int* __restrict__ cnt, const int* __restrict__ ell,
    const float* __restrict__ ed, const float* __restrict__ g,
    const float* __restrict__ denom, const float* __restrict__ bias,
    const int* __restrict__ ovf_cnt, const int* __restrict__ ovf_s,
    const int* __restrict__ ovf_d, float* __restrict__ out)
{
    const int t = threadIdx.x;
    const int n = blockIdx.x * 8 + (t >> 5);
    if (n >= N_NODES) return;
    const int lane = t & 31;
    const int head = lane >> 3;

    /* self loop */
    float4 acc = ld4(g + n * 128 + lane * 4);

    const int raw = cnt[n];
    const int deg = min(raw, ELLW);
    const int* __restrict__ row = ell + n * ELLW;
    int j = 0;
    for (; j + 3 < deg; j += 4) {               /* 4 rows in flight */
        int s0 = row[j],     s1 = row[j + 1];
        int s2 = row[j + 2], s3 = row[j + 3];
        float4 g0 = ld4(g + s0 * 128 + lane * 4);
        float4 g1 = ld4(g + s1 * 128 + lane * 4);
        float4 g2 = ld4(g + s2 * 128 + lane * 4);
        float4 g3 = ld4(g + s3 * 128 + lane * 4);
        acc.x += g0.x + g1.x + g2.x + g3.x;
        acc.y += g0.y + g1.y + g2.y + g3.y;
        acc.z += g0.z + g1.z + g2.z + g3.z;
        acc.w += g0.w + g1.w + g2.w + g3.w;
    }
    for (; j < deg; ++j) {
        int s0 = row[j];
        float4 g0 = ld4(g + s0 * 128 + lane * 4);
        acc.x += g0.x; acc.y += g0.y; acc.z += g0.z; acc.w += g0.w;
    }

    if (raw > ELLW) {                            /* expected never */
        int m = min(*ovf_cnt, OVF_CAP);
        for (int i = 0; i < m; ++i) {
            if (ovf_d[i] == n) {
                int s = ovf_s[i];
                float4 g0 = ld4(g + s * 128 + lane * 4);
                acc.x += g0.x; acc.y += g0.y; acc.z += g0.z; acc.w += g0.w;
            }
        }
    }

    float dsum = 0.f;
    #pragma unroll
    for (int i2 = 0; i2 < DEN_SLOTS; ++i2) dsum += denom[i2 * 4 + head];

    const float sc = ed[n * 4 + head] / dsum;
    float4 b = ld4(bias + lane * 4);
    float4 o = make_float4(acc.x * sc + b.x, acc.y * sc + b.y,
                           acc.z * sc + b.z, acc.w * sc + b.w);
    *reinterpret_cast<float4*>(out + n * 128 + lane * 4) = o;
}

extern "C" void kernel_launch(void* const* d_in, const int* in_sizes, int n_in,
                              void* d_out, int out_size, void* d_ws, size_t ws_size,
                              hipStream_t stream) {
    const float* x    = (const float*)d_in[0];
    const int*   eidx = (const int*)d_in[1];   /* [2][800000], row0=src row1=dst */
    const float* W    = (const float*)d_in[2];
    const float* att  = (const float*)d_in[3];
    const float* bias = (const float*)d_in[4];
    float* out = (float*)d_out;
    float* ws  = (float*)d_ws;

    float* g      = ws + WS_G;
    float* es     = ws + WS_ES;
    float* ed     = ws + WS_ED;
    float* denom  = ws + WS_DEN;
    int*   cnt    = (int*)(ws + WS_CNT);
    int*   ell    = (int*)(ws + WS_ELL);
    int*   ovfc   = (int*)(ws + WS_OVFC);
    int*   ovfs   = (int*)(ws + WS_OVFS);
    int*   ovfd   = (int*)(ws + WS_OVFD);

    k_gemm_attprep   <<<(N_NODES + 31) / 32, 256, 0, stream>>>(x, W, att, g, es, ed, cnt, ovfc, denom);
    k_edge_fill_denom<<<NBLK_EDGE,           256, 0, stream>>>(eidx, es, ed, cnt, ell, ovfc, ovfs, ovfd, denom);
    k_gather         <<<(N_NODES + 7) / 8,   256, 0, stream>>>(cnt, ell, ed, g, denom, bias, ovfc, ovfs, ovfd, out);
}

// Round 11
// 228.588 us; speedup vs baseline: 1.0137x; 1.0137x over previous
//
#include <hip/hip_runtime.h>
#include <math.h>

#define N_NODES 50000
#define N_EDGES 800000
#define E_TOT   850000   /* edges + self loops */
#define IN_F    128
#define HEADS   4
#define OUT_F   32
#define HF      128      /* HEADS*OUT_F */
#define NEG_SLOPE 0.2f
#define ELLW    40       /* slots per node; P(deg>40 | Poisson 16) ~ 2e-9 */
#define OVF_CAP 4096
#define DEN_SLOTS 16     /* spread denominator atomics 16-way */
#define NXCD    8
#define DPX     6250     /* N_NODES / NXCD, exact */

/* workspace layout (float offsets; int/u16 arrays cast in place) */
#define WS_G      0           /* g (bf16): 50000*128 u16 = 3,200,000 floats */
#define WS_ES     3200000     /* exp(a_src): 200,000 floats */
#define WS_ED     3400000     /* exp(a_dst): 200,000 floats */
#define WS_DEN    3600000     /* denom[16][4] */
#define WS_CNT    3610000     /* int[50000] */
#define WS_ELL    3660000     /* u16[50000*40] = 1,000,000 floats */
#define WS_OVFC   4660000     /* int[1] + pad */
#define WS_OVFS   4660064     /* int[OVF_CAP] */
#define WS_OVFD   4664160     /* int[OVF_CAP] */
#define NBLK_EDGE 3321        /* ceil(850000/256) */

static __device__ __forceinline__ float4 ld4(const float* p) {
    return *reinterpret_cast<const float4*>(p);
}
static __device__ __forceinline__ unsigned short f2bf(float f) {
    unsigned u = __float_as_uint(f);
    return (unsigned short)((u + 0x7FFFu + ((u >> 16) & 1u)) >> 16);  /* RNE */
}
static __device__ __forceinline__ float4 bf2f4(ushort4 v) {
    return make_float4(__uint_as_float((unsigned)v.x << 16),
                       __uint_as_float((unsigned)v.y << 16),
                       __uint_as_float((unsigned)v.z << 16),
                       __uint_as_float((unsigned)v.w << 16));
}

/* D1: GEMM + fused epilogue: g(bf16) = (x@W^T)*exp(a_src), es/ed tables;
   zeroes cnt / ovf_cnt / denom. block: 256 threads, 32 nodes. */
__global__ __launch_bounds__(256) void k_gemm_attprep(
    const float* __restrict__ x, const float* __restrict__ W,
    const float* __restrict__ att, unsigned short* __restrict__ g,
    float* __restrict__ es, float* __restrict__ ed,
    int* __restrict__ cnt, int* __restrict__ ovf_cnt,
    float* __restrict__ denom)
{
    __shared__ float wt[32 * 128];   /* 16 KB (K-chunk of W^T) */
    const int t  = threadIdx.x;
    const int n0 = blockIdx.x * 32;

    if (t < 32) {
        int z = n0 + t;
        if (z < N_NODES) cnt[z] = 0;
    }
    if (blockIdx.x == 0) {
        if (t == 0) *ovf_cnt = 0;
        if (t < DEN_SLOTS * 4) denom[t] = 0.f;
    }

    const int cg = t & 31;
    const int nr = t >> 5;
    float4 acc[4];
    #pragma unroll
    for (int ni = 0; ni < 4; ++ni) acc[ni] = make_float4(0.f, 0.f, 0.f, 0.f);

    const float4* wt4 = reinterpret_cast<const float4*>(wt);
    const float4* x4  = reinterpret_cast<const float4*>(x);

    int row[4];
    #pragma unroll
    for (int ni = 0; ni < 4; ++ni) {
        int n = n0 + nr + ni * 8;
        row[ni] = n < N_NODES ? n : N_NODES - 1;
    }

    for (int kt = 0; kt < 4; ++kt) {
        __syncthreads();
        {   /* stage W^T chunk: wt[kk][c] = W[c][kt*32+kk] */
            const int c = t >> 1, half = t & 1;
            #pragma unroll
            for (int i = 0; i < 4; ++i) {
                float4 wv = ld4(W + c * 128 + kt * 32 + half * 16 + i * 4);
                int kk = half * 16 + i * 4;
                wt[(kk + 0) * 128 + c] = wv.x;
                wt[(kk + 1) * 128 + c] = wv.y;
                wt[(kk + 2) * 128 + c] = wv.z;
                wt[(kk + 3) * 128 + c] = wv.w;
            }
        }
        __syncthreads();

        #pragma unroll
        for (int kk4 = 0; kk4 < 8; ++kk4) {
            float xv[4][4];
            #pragma unroll
            for (int ni = 0; ni < 4; ++ni)
                *reinterpret_cast<float4*>(xv[ni]) =
                    x4[row[ni] * 32 + kt * 8 + kk4];      /* broadcast load */
            #pragma unroll
            for (int j = 0; j < 4; ++j) {
                float4 wv = wt4[(kk4 * 4 + j) * 32 + cg];
                #pragma unroll
                for (int ni = 0; ni < 4; ++ni) {
                    acc[ni].x += xv[ni][j] * wv.x;
                    acc[ni].y += xv[ni][j] * wv.y;
                    acc[ni].z += xv[ni][j] * wv.z;
                    acc[ni].w += xv[ni][j] * wv.w;
                }
            }
        }
    }

    const int head = cg >> 3;
    const int f0   = (cg & 7) * 4;
    float4 as = ld4(att + head * 64 + f0);
    float4 ad = ld4(att + head * 64 + 32 + f0);

    #pragma unroll
    for (int ni = 0; ni < 4; ++ni) {
        int n = n0 + nr + ni * 8;
        if (n < N_NODES) {
            float lx = acc[ni].x > 0.f ? acc[ni].x : NEG_SLOPE * acc[ni].x;
            float ly = acc[ni].y > 0.f ? acc[ni].y : NEG_SLOPE * acc[ni].y;
            float lz = acc[ni].z > 0.f ? acc[ni].z : NEG_SLOPE * acc[ni].z;
            float lw = acc[ni].w > 0.f ? acc[ni].w : NEG_SLOPE * acc[ni].w;
            float ps = lx * as.x + ly * as.y + lz * as.z + lw * as.w;
            float pd = lx * ad.x + ly * ad.y + lz * ad.z + lw * ad.w;
            ps += __shfl_xor(ps, 1); ps += __shfl_xor(ps, 2); ps += __shfl_xor(ps, 4);
            pd += __shfl_xor(pd, 1); pd += __shfl_xor(pd, 2); pd += __shfl_xor(pd, 4);
            float esv = expf(ps);                      /* all 8 lanes agree */
            ushort4 sv;
            sv.x = f2bf(acc[ni].x * esv);
            sv.y = f2bf(acc[ni].y * esv);
            sv.z = f2bf(acc[ni].z * esv);
            sv.w = f2bf(acc[ni].w * esv);
            *reinterpret_cast<ushort4*>(&g[n * 128 + cg * 4]) = sv;
            if ((t & 7) == 0) {
                es[n * 4 + head] = esv;
                ed[n * 4 + head] = expf(pd);
            }
        }
    }
}

/* D2: XCD-partitioned edge pass.  grid = NBLK_EDGE*8.
   block b: chunk = b>>3 (256 edges), xcd = b&7.
   Part A (all blocks): ELL fill for dsts in this XCD's slice only ->
   ELL/cnt lines stay in one XCD's L2 (no cross-XCD line ping-pong).
   Part B (xcd==0 blocks): denominator partials for the whole chunk. */
__global__ __launch_bounds__(256) void k_edge_fill_denom(
    const int* __restrict__ eidx, const float* __restrict__ es,
    const float* __restrict__ ed, int* __restrict__ cnt,
    unsigned short* __restrict__ ell, int* __restrict__ ovf_cnt,
    int* __restrict__ ovf_s, int* __restrict__ ovf_d,
    float* __restrict__ denom)
{
    __shared__ float4 red[256];
    const int t     = threadIdx.x;
    const int chunk = blockIdx.x >> 3;
    const int xcd   = blockIdx.x & 7;
    const int e     = chunk * 256 + t;

    /* part A: ELL fill, filtered to this XCD's dst range */
    if (e < N_EDGES) {
        int d = eidx[N_EDGES + e];
        if (d >= xcd * DPX && d < (xcd + 1) * DPX) {
            int s = eidx[e];
            int pos = atomicAdd(&cnt[d], 1);
            if (pos < ELLW) {
                ell[d * ELLW + pos] = (unsigned short)s;
            } else {
                int o = atomicAdd(ovf_cnt, 1);
                if (o < OVF_CAP) { ovf_s[o] = s; ovf_d[o] = d; }
            }
        }
    }

    /* part B: denominator (xcd-0 blocks process their whole chunk) */
    if (xcd == 0) {
        float4 w = make_float4(0.f, 0.f, 0.f, 0.f);
        if (e < E_TOT) {
            int s, d;
            if (e < N_EDGES) { s = eidx[e]; d = eidx[N_EDGES + e]; }
            else             { s = d = e - N_EDGES; }   /* self loop */
            float4 vs = ld4(es + s * 4);
            float4 vd = ld4(ed + d * 4);
            w.x = vs.x * vd.x;
            w.y = vs.y * vd.y;
            w.z = vs.z * vd.z;
            w.w = vs.w * vd.w;
        }
        red[t] = w;
        __syncthreads();
        for (int sdt = 128; sdt > 0; sdt >>= 1) {
            if (t < sdt) {
                float4 o = red[t + sdt];
                red[t].x += o.x; red[t].y += o.y; red[t].z += o.z; red[t].w += o.w;
            }
            __syncthreads();
        }
        if (t < 4)
            atomicAdd(&denom[(chunk & (DEN_SLOTS - 1)) * 4 + t],
                      reinterpret_cast<const float*>(&red[0])[t]);
    }
}

/* D3: gather (ELL, bf16 g): sparse row-sum, scale by ed[n]/denom, +bias. */
__global__ __launch_bounds__(256) void k_gather(
    const int* __restrict__ cnt, const unsigned short* __restrict__ ell,
    const float* __restrict__ ed, const unsigned short* __restrict__ g,
    const float* __restrict__ denom, const float* __restrict__ bias,
    const int* __restrict__ ovf_cnt, const int* __restrict__ ovf_s,
    const int* __restrict__ ovf_d, float* __restrict__ out)
{
    const int t = threadIdx.x;
    const int n = blockIdx.x * 8 + (t >> 5);
    if (n >= N_NODES) return;
    const int lane = t & 31;
    const int head = lane >> 3;

    const ushort4* g4 = reinterpret_cast<const ushort4*>(g);

    /* self loop */
    float4 acc = bf2f4(g4[n * 32 + lane]);

    const int raw = cnt[n];
    const int deg = min(raw, ELLW);
    const unsigned short* __restrict__ row = ell + n * ELLW;
    int j = 0;
    for (; j + 3 < deg; j += 4) {               /* 4 rows in flight */
        int s0 = row[j],     s1 = row[j + 1];
        int s2 = row[j + 2], s3 = row[j + 3];
        float4 g0 = bf2f4(g4[s0 * 32 + lane]);
        float4 g1 = bf2f4(g4[s1 * 32 + lane]);
        float4 g2 = bf2f4(g4[s2 * 32 + lane]);
        float4 g3 = bf2f4(g4[s3 * 32 + lane]);
        acc.x += g0.x + g1.x + g2.x + g3.x;
        acc.y += g0.y + g1.y + g2.y + g3.y;
        acc.z += g0.z + g1.z + g2.z + g3.z;
        acc.w += g0.w + g1.w + g2.w + g3.w;
    }
    for (; j < deg; ++j) {
        int s0 = row[j];
        float4 g0 = bf2f4(g4[s0 * 32 + lane]);
        acc.x += g0.x; acc.y += g0.y; acc.z += g0.z; acc.w += g0.w;
    }

    if (raw > ELLW) {                            /* expected never */
        int m = min(*ovf_cnt, OVF_CAP);
        for (int i = 0; i < m; ++i) {
            if (ovf_d[i] == n) {
                float4 g0 = bf2f4(g4[ovf_s[i] * 32 + lane]);
                acc.x += g0.x; acc.y += g0.y; acc.z += g0.z; acc.w += g0.w;
            }
        }
    }

    float dsum = 0.f;
    #pragma unroll
    for (int i2 = 0; i2 < DEN_SLOTS; ++i2) dsum += denom[i2 * 4 + head];

    const float sc = ed[n * 4 + head] / dsum;
    float4 b = ld4(bias + lane * 4);
    float4 o = make_float4(acc.x * sc + b.x, acc.y * sc + b.y,
                           acc.z * sc + b.z, acc.w * sc + b.w);
    *reinterpret_cast<float4*>(out + n * 128 + lane * 4) = o;
}

extern "C" void kernel_launch(void* const* d_in, const int* in_sizes, int n_in,
                              void* d_out, int out_size, void* d_ws, size_t ws_size,
                              hipStream_t stream) {
    const float* x    = (const float*)d_in[0];
    const int*   eidx = (const int*)d_in[1];   /* [2][800000], row0=src row1=dst */
    const float* W    = (const float*)d_in[2];
    const float* att  = (const float*)d_in[3];
    const float* bias = (const float*)d_in[4];
    float* out = (float*)d_out;
    float* ws  = (float*)d_ws;

    unsigned short* g   = (unsigned short*)(ws + WS_G);
    float* es     = ws + WS_ES;
    float* ed     = ws + WS_ED;
    float* denom  = ws + WS_DEN;
    int*   cnt    = (int*)(ws + WS_CNT);
    unsigned short* ell = (unsigned short*)(ws + WS_ELL);
    int*   ovfc   = (int*)(ws + WS_OVFC);
    int*   ovfs   = (int*)(ws + WS_OVFS);
    int*   ovfd   = (int*)(ws + WS_OVFD);

    k_gemm_attprep   <<<(N_NODES + 31) / 32, 256, 0, stream>>>(x, W, att, g, es, ed, cnt, ovfc, denom);
    k_edge_fill_denom<<<NBLK_EDGE * NXCD,    256, 0, stream>>>(eidx, es, ed, cnt, ell, ovfc, ovfs, ovfd, denom);
    k_gather         <<<(N_NODES + 7) / 8,   256, 0, stream>>>(cnt, ell, ed, g, denom, bias, ovfc, ovfs, ovfd, out);
}

// Round 12
// 187.712 us; speedup vs baseline: 1.2345x; 1.2178x over previous
//
#include <hip/hip_runtime.h>
#include <math.h>

#define N_NODES 50000
#define N_EDGES 800000
#define E_TOT   850000   /* edges + self loops */
#define IN_F    128
#define HEADS   4
#define OUT_F   32
#define HF      128      /* HEADS*OUT_F */
#define NEG_SLOPE 0.2f
#define ELLW    40       /* slots per node; P(deg>40 | Poisson 16) ~ 2e-9 */
#define OVF_CAP 4096
#define DEN_SLOTS 16     /* spread denominator atomics 16-way */

/* workspace layout (float offsets; int/u16 arrays cast in place) */
#define WS_G      0           /* g (bf16): 50000*128 u16 = 3,200,000 floats */
#define WS_ES     3200000     /* exp(a_src): 200,000 floats */
#define WS_ED     3400000     /* exp(a_dst): 200,000 floats */
#define WS_DEN    3600000     /* denom[16][4] */
#define WS_CNT    3610000     /* int[50000] */
#define WS_ELL    3660000     /* u16[50000*40] = 1,000,000 floats */
#define WS_OVFC   4660000     /* int[1] + pad */
#define WS_OVFS   4660064     /* int[OVF_CAP] */
#define WS_OVFD   4664160     /* int[OVF_CAP] */
#define NBLK_EDGE 3321        /* ceil(850000/256) */

typedef __attribute__((ext_vector_type(8))) short bf16x8;
typedef __attribute__((ext_vector_type(4))) float f32x4;

static __device__ __forceinline__ float4 ld4(const float* p) {
    return *reinterpret_cast<const float4*>(p);
}
static __device__ __forceinline__ unsigned short f2bf(float f) {
    unsigned u = __float_as_uint(f);
    return (unsigned short)((u + 0x7FFFu + ((u >> 16) & 1u)) >> 16);  /* RNE */
}
static __device__ __forceinline__ float4 bf2f4(ushort4 v) {
    return make_float4(__uint_as_float((unsigned)v.x << 16),
                       __uint_as_float((unsigned)v.y << 16),
                       __uint_as_float((unsigned)v.z << 16),
                       __uint_as_float((unsigned)v.w << 16));
}

/* D1: MFMA GEMM + fused epilogue.
   block: 256 threads = 4 waves, 64 nodes (16/wave), all 128 cols.
   W^T staged once in LDS as bf16 (32 KB), XOR-swizzled 16B chunks:
   chunk (c,k8) at byte c*256 + ((k8*16) ^ ((c&7)<<4))  -> <=2-way bank alias.
   A-frag: lane l holds x[row=l&15][k=(l>>4)*8+i]; B-frag: W^T[k][col=l&15].
   C/D:    acc[ct][j] = h[row=(l>>4)*4+j][col=ct*16+(l&15)]  (m89-verified). */
__global__ __launch_bounds__(256) void k_gemm_attprep(
    const float* __restrict__ x, const float* __restrict__ W,
    const float* __restrict__ att, unsigned short* __restrict__ g,
    float* __restrict__ es, float* __restrict__ ed,
    int* __restrict__ cnt, int* __restrict__ ovf_cnt,
    float* __restrict__ denom)
{
    __shared__ unsigned short wbf[128 * 128];   /* 32 KB */
    const int t  = threadIdx.x;
    const int n0 = blockIdx.x * 64;

    /* fold in: zero cnt / ovf / denom for the later passes */
    if (t < 64) {
        int z = n0 + t;
        if (z < N_NODES) cnt[z] = 0;
    }
    if (blockIdx.x == 0) {
        if (t == 0) *ovf_cnt = 0;
        if (t < DEN_SLOTS * 4) denom[t] = 0.f;
    }

    /* stage W -> bf16 LDS, swizzled. thread t: row c = t>>1, 8 chunks of 8 k */
    {
        const int c  = t >> 1;
        const int kh = (t & 1) * 8;
        #pragma unroll
        for (int i = 0; i < 8; ++i) {
            int k8 = kh + i;
            float4 a = ld4(W + c * 128 + k8 * 8);
            float4 b = ld4(W + c * 128 + k8 * 8 + 4);
            ushort4 lo, hi;
            lo.x = f2bf(a.x); lo.y = f2bf(a.y); lo.z = f2bf(a.z); lo.w = f2bf(a.w);
            hi.x = f2bf(b.x); hi.y = f2bf(b.y); hi.z = f2bf(b.z); hi.w = f2bf(b.w);
            int byteoff = c * 256 + ((k8 * 16) ^ ((c & 7) << 4));
            *reinterpret_cast<ushort4*>((char*)wbf + byteoff)     = lo;
            *reinterpret_cast<ushort4*>((char*)wbf + byteoff + 8) = hi;
        }
    }
    __syncthreads();

    const int w = t >> 6;            /* wave 0..3: rows n0+16w .. +15 */
    const int l = t & 63;
    const int li = l & 15;           /* A-row / B-col / C-col index   */
    const int lk = l >> 4;           /* k-chunk selector              */

    int arow = n0 + w * 16 + li;
    if (arow >= N_NODES) arow = N_NODES - 1;     /* clamp; stores guarded */

    f32x4 acc[8];
    #pragma unroll
    for (int ct = 0; ct < 8; ++ct) acc[ct] = (f32x4){0.f, 0.f, 0.f, 0.f};

    #pragma unroll
    for (int kt = 0; kt < 4; ++kt) {
        const float* xp = x + arow * 128 + kt * 32 + lk * 8;
        float4 a = ld4(xp), b = ld4(xp + 4);
        bf16x8 af;
        af[0] = (short)f2bf(a.x); af[1] = (short)f2bf(a.y);
        af[2] = (short)f2bf(a.z); af[3] = (short)f2bf(a.w);
        af[4] = (short)f2bf(b.x); af[5] = (short)f2bf(b.y);
        af[6] = (short)f2bf(b.z); af[7] = (short)f2bf(b.w);
        #pragma unroll
        for (int ct = 0; ct < 8; ++ct) {
            int col = ct * 16 + li;
            int k8  = kt * 4 + lk;
            int byteoff = col * 256 + ((k8 * 16) ^ ((col & 7) << 4));
            bf16x8 bf = *reinterpret_cast<const bf16x8*>((const char*)wbf + byteoff);
            acc[ct] = __builtin_amdgcn_mfma_f32_16x16x32_bf16(af, bf, acc[ct], 0, 0, 0);
        }
    }

    /* att coefficients for this lane's 8 columns */
    float as_[8], ad_[8];
    #pragma unroll
    for (int ct = 0; ct < 8; ++ct) {
        int col = ct * 16 + li;
        int hd = col >> 5, f = col & 31;
        as_[ct] = att[hd * 64 + f];
        ad_[ct] = att[hd * 64 + 32 + f];
    }

    #pragma unroll
    for (int j = 0; j < 4; ++j) {
        int n = n0 + w * 16 + lk * 4 + j;
        float ps[4] = {0.f, 0.f, 0.f, 0.f};
        float pd[4] = {0.f, 0.f, 0.f, 0.f};
        #pragma unroll
        for (int ct = 0; ct < 8; ++ct) {
            float v  = acc[ct][j];
            float lv = v > 0.f ? v : NEG_SLOPE * v;
            ps[ct >> 1] += lv * as_[ct];
            pd[ct >> 1] += lv * ad_[ct];
        }
        /* reduce over the 16-lane col group */
        #pragma unroll
        for (int hd = 0; hd < 4; ++hd) {
            ps[hd] += __shfl_xor(ps[hd], 1); ps[hd] += __shfl_xor(ps[hd], 2);
            ps[hd] += __shfl_xor(ps[hd], 4); ps[hd] += __shfl_xor(ps[hd], 8);
            pd[hd] += __shfl_xor(pd[hd], 1); pd[hd] += __shfl_xor(pd[hd], 2);
            pd[hd] += __shfl_xor(pd[hd], 4); pd[hd] += __shfl_xor(pd[hd], 8);
        }
        if (n < N_NODES) {
            float esv[4];
            #pragma unroll
            for (int hd = 0; hd < 4; ++hd) esv[hd] = expf(ps[hd]);
            #pragma unroll
            for (int ct = 0; ct < 8; ++ct)
                g[n * 128 + ct * 16 + li] = f2bf(acc[ct][j] * esv[ct >> 1]);
            if (li < 4) {                 /* one lane per head */
                es[n * 4 + li] = esv[li];
                ed[n * 4 + li] = expf(pd[li]);
            }
        }
    }
}

/* D2: ONE edge pass (reverted R10 structure): ELL slot assign + denominator
   partials into 16 spread slots. [0,800K): edges; [800K,850K): self loops. */
__global__ __launch_bounds__(256) void k_edge_fill_denom(
    const int* __restrict__ eidx, const float* __restrict__ es,
    const float* __restrict__ ed, int* __restrict__ cnt,
    unsigned short* __restrict__ ell, int* __restrict__ ovf_cnt,
    int* __restrict__ ovf_s, int* __restrict__ ovf_d,
    float* __restrict__ denom)
{
    __shared__ float4 red[256];
    const int t = threadIdx.x;
    const int e = blockIdx.x * 256 + t;
    float4 w = make_float4(0.f, 0.f, 0.f, 0.f);
    if (e < E_TOT) {
        int s, d;
        if (e < N_EDGES) {
            s = eidx[e]; d = eidx[N_EDGES + e];
            int pos = atomicAdd(&cnt[d], 1);
            if (pos < ELLW) {
                ell[d * ELLW + pos] = (unsigned short)s;
            } else {
                int o = atomicAdd(ovf_cnt, 1);
                if (o < OVF_CAP) { ovf_s[o] = s; ovf_d[o] = d; }
            }
        } else {
            s = d = e - N_EDGES;          /* self loop: denom term only */
        }
        float4 vs = ld4(es + s * 4);
        float4 vd = ld4(ed + d * 4);
        w.x = vs.x * vd.x;
        w.y = vs.y * vd.y;
        w.z = vs.z * vd.z;
        w.w = vs.w * vd.w;
    }
    red[t] = w;
    __syncthreads();
    for (int sdt = 128; sdt > 0; sdt >>= 1) {
        if (t < sdt) {
            float4 o = red[t + sdt];
            red[t].x += o.x; red[t].y += o.y; red[t].z += o.z; red[t].w += o.w;
        }
        __syncthreads();
    }
    if (t < 4)
        atomicAdd(&denom[(blockIdx.x & (DEN_SLOTS - 1)) * 4 + t],
                  reinterpret_cast<const float*>(&red[0])[t]);
}

/* D3: gather (ELL, bf16 g): sparse row-sum, scale by ed[n]/denom, +bias. */
__global__ __launch_bounds__(256) void k_gather(
    const int* __restrict__ cnt, const unsigned short* __restrict__ ell,
    const float* __restrict__ ed, const unsigned short* __restrict__ g,
    const float* __restrict__ denom, const float* __restrict__ bias,
    const int* __restrict__ ovf_cnt, const int* __restrict__ ovf_s,
    const int* __restrict__ ovf_d, float* __restrict__ out)
{
    const int t = threadIdx.x;
    const int n = blockIdx.x * 8 + (t >> 5);
    if (n >= N_NODES) return;
    const int lane = t & 31;
    const int head = lane >> 3;

    const ushort4* g4 = reinterpret_cast<const ushort4*>(g);

    /* self loop */
    float4 acc = bf2f4(g4[n * 32 + lane]);

    const int raw = cnt[n];
    const int deg = min(raw, ELLW);
    const unsigned short* __restrict__ row = ell + n * ELLW;
    int j = 0;
    for (; j + 3 < deg; j += 4) {               /* 4 rows in flight */
        int s0 = row[j],     s1 = row[j + 1];
        int s2 = row[j + 2], s3 = row[j + 3];
        float4 g0 = bf2f4(g4[s0 * 32 + lane]);
        float4 g1 = bf2f4(g4[s1 * 32 + lane]);
        float4 g2 = bf2f4(g4[s2 * 32 + lane]);
        float4 g3 = bf2f4(g4[s3 * 32 + lane]);
        acc.x += g0.x + g1.x + g2.x + g3.x;
        acc.y += g0.y + g1.y + g2.y + g3.y;
        acc.z += g0.z + g1.z + g2.z + g3.z;
        acc.w += g0.w + g1.w + g2.w + g3.w;
    }
    for (; j < deg; ++j) {
        int s0 = row[j];
        float4 g0 = bf2f4(g4[s0 * 32 + lane]);
        acc.x += g0.x; acc.y += g0.y; acc.z += g0.z; acc.w += g0.w;
    }

    if (raw > ELLW) {                            /* expected never */
        int m = min(*ovf_cnt, OVF_CAP);
        for (int i = 0; i < m; ++i) {
            if (ovf_d[i] == n) {
                float4 g0 = bf2f4(g4[ovf_s[i] * 32 + lane]);
                acc.x += g0.x; acc.y += g0.y; acc.z += g0.z; acc.w += g0.w;
            }
        }
    }

    float dsum = 0.f;
    #pragma unroll
    for (int i2 = 0; i2 < DEN_SLOTS; ++i2) dsum += denom[i2 * 4 + head];

    const float sc = ed[n * 4 + head] / dsum;
    float4 b = ld4(bias + lane * 4);
    float4 o = make_float4(acc.x * sc + b.x, acc.y * sc + b.y,
                           acc.z * sc + b.z, acc.w * sc + b.w);
    *reinterpret_cast<float4*>(out + n * 128 + lane * 4) = o;
}

extern "C" void kernel_launch(void* const* d_in, const int* in_sizes, int n_in,
                              void* d_out, int out_size, void* d_ws, size_t ws_size,
                              hipStream_t stream) {
    const float* x    = (const float*)d_in[0];
    const int*   eidx = (const int*)d_in[1];   /* [2][800000], row0=src row1=dst */
    const float* W    = (const float*)d_in[2];
    const float* att  = (const float*)d_in[3];
    const float* bias = (const float*)d_in[4];
    float* out = (float*)d_out;
    float* ws  = (float*)d_ws;

    unsigned short* g   = (unsigned short*)(ws + WS_G);
    float* es     = ws + WS_ES;
    float* ed     = ws + WS_ED;
    float* denom  = ws + WS_DEN;
    int*   cnt    = (int*)(ws + WS_CNT);
    unsigned short* ell = (unsigned short*)(ws + WS_ELL);
    int*   ovfc   = (int*)(ws + WS_OVFC);
    int*   ovfs   = (int*)(ws + WS_OVFS);
    int*   ovfd   = (int*)(ws + WS_OVFD);

    k_gemm_attprep   <<<(N_NODES + 63) / 64, 256, 0, stream>>>(x, W, att, g, es, ed, cnt, ovfc, denom);
    k_edge_fill_denom<<<NBLK_EDGE,           256, 0, stream>>>(eidx, es, ed, cnt, ell, ovfc, ovfs, ovfd, denom);
    k_gather         <<<(N_NODES + 7) / 8,   256, 0, stream>>>(cnt, ell, ed, g, denom, bias, ovfc, ovfs, ovfd, out);
}